// Round 21
// baseline (188.949 us; speedup 1.0000x reference)
//
#include <hip/hip_runtime.h>
#include <hip/hip_bf16.h>

#define NN 4096

typedef unsigned short u16;
typedef __attribute__((ext_vector_type(8))) short bf16x8;
typedef __attribute__((ext_vector_type(4))) float f32x4;

// fp32 -> bf16 round-to-nearest-even
static __device__ __forceinline__ u16 f2bf(float x) {
  unsigned u = __float_as_uint(x);
  u += 0x7fff + ((u >> 16) & 1);
  return (u16)(u >> 16);
}
static __device__ __forceinline__ float bf2f(u16 h) {
  return __uint_as_float((unsigned)h << 16);
}

// async global->LDS, 16B per lane; LDS dest = wave-uniform base + lane*16
static __device__ __forceinline__ void gload_lds16(const void* g, void* l) {
  __builtin_amdgcn_global_load_lds(
      (const __attribute__((address_space(1))) void*)g,
      (__attribute__((address_space(3))) void*)l, 16, 0, 0);
}

// F(M) = sum_{j=0}^{M-1} floor(j/2^lg)
static __device__ __forceinline__ int Fpre(int M, int lg) {
  if (M <= 0) return 0;
  const int q = (M - 1) >> lg, r = (M - 1) & ((1 << lg) - 1);
  return ((q * (q - 1)) << (lg - 1)) + q * (r + 1);
}

// ---------------------------------------------------------------------------
// Pass 1 (fused, grid 2144): R20 convert (proven): A-path 16B stores /
// 16 loads in flight; B-path 64k x 128n transpose tiles, 8 loads in flight.
// ---------------------------------------------------------------------------
__global__ __launch_bounds__(256) void convert_fused(
    const float* __restrict__ A, const float* __restrict__ B,
    u16* __restrict__ Ab, u16* __restrict__ Bt) {
  __shared__ float t[64][129];  // 33 KB
  const int blk = blockIdx.x;
  const int tid = threadIdx.x;

  if (blk < 1024) {  // ---- A path: 128x128 block (bi,kb) ----
    const int kb = blk & 31, bi = blk >> 5;
    if (kb > bi) {
      if (kb == bi + 1 && !(bi & 1)) {  // super-diagonal Ab: real zeros
        const uint4 zz = {0u, 0u, 0u, 0u};
        const int r0 = tid >> 4;
        const int cq = (tid & 15) * 8;
#pragma unroll
        for (int h = 0; h < 8; ++h)
          *(uint4*)&Ab[(long)(bi * 128 + h * 16 + r0) * NN + kb * 128 + cq] =
              zz;
      }
      return;
    }
    const int r0 = tid >> 4;        // 0..15
    const int cq = (tid & 15) * 8;  // 8 cols per thread
    const bool diag = (kb == bi);
    float4 v0[8], v1[8];
#pragma unroll
    for (int h = 0; h < 8; ++h) {  // 16 loads in flight
      const float* src =
          &A[(long)(bi * 128 + h * 16 + r0) * NN + kb * 128 + cq];
      v0[h] = *(const float4*)src;
      v1[h] = *(const float4*)(src + 4);
    }
#pragma unroll
    for (int h = 0; h < 8; ++h) {
      const int row = h * 16 + r0;
      union { u16 e[8]; uint4 v; } o;
      o.e[0] = f2bf(v0[h].x); o.e[1] = f2bf(v0[h].y);
      o.e[2] = f2bf(v0[h].z); o.e[3] = f2bf(v0[h].w);
      o.e[4] = f2bf(v1[h].x); o.e[5] = f2bf(v1[h].y);
      o.e[6] = f2bf(v1[h].z); o.e[7] = f2bf(v1[h].w);
      if (diag) {
        const int i = bi * 128 + row, k = kb * 128 + cq;
#pragma unroll
        for (int e = 0; e < 8; ++e)
          if (k + e > i) o.e[e] = 0;
      }
      *(uint4*)&Ab[(long)(bi * 128 + row) * NN + kb * 128 + cq] = o.v;
    }
    return;
  }

  if (blk >= 2080) {  // ---- sub-diagonal Bt zero blocks ----
    const int idx = blk - 2080;  // 0..63
    const int q = idx >> 2;
    const int n0 = (2 * (2 * q + 1) + (idx & 1)) * 64;
    const int k0 = (2 * (2 * q) + ((idx >> 1) & 1)) * 64;
    const int n = tid >> 3;
    const int kc = (tid & 7) * 8;
    const uint4 z = {0u, 0u, 0u, 0u};
#pragma unroll
    for (int p = 0; p < 2; ++p)
      *(uint4*)&Bt[(long)(n0 + n + p * 32) * NN + k0 + kc] = z;
    return;
  }

  // ---- B path: 64k x 128n transpose tile over needed (N<=K) 128-pairs ----
  const int t2 = blk - 1024;  // 0..1055
  int prem = t2 >> 1, N = 0;  // pair index 0..527
  while (prem >= 32 - N) { prem -= 32 - N; ++N; }
  const int K = N + prem;     // N <= K
  const int n0 = N * 128;
  const int k0 = K * 128 + (t2 & 1) * 64;

  float4 w[8];
#pragma unroll
  for (int p = 0; p < 8; ++p) {  // 8 loads in flight (ILP)
    const int idx = p * 256 + tid;
    const int r = idx >> 5;          // 0..63 (k row)
    const int c4 = (idx & 31) * 4;   // 0..124 (n col quad)
    w[p] = *(const float4*)&B[(long)(k0 + r) * NN + n0 + c4];
  }
#pragma unroll
  for (int p = 0; p < 8; ++p) {
    const int idx = p * 256 + tid;
    const int r = idx >> 5;
    const int c4 = (idx & 31) * 4;
    const int kg = k0 + r;
    t[r][c4 + 0] = (n0 + c4 + 0 <= kg) ? w[p].x : 0.f;
    t[r][c4 + 1] = (n0 + c4 + 1 <= kg) ? w[p].y : 0.f;
    t[r][c4 + 2] = (n0 + c4 + 2 <= kg) ? w[p].z : 0.f;
    t[r][c4 + 3] = (n0 + c4 + 3 <= kg) ? w[p].w : 0.f;
  }
  __syncthreads();

#pragma unroll
  for (int q = 0; q < 4; ++q) {
    const int idx = q * 256 + tid;
    const int n = idx >> 3;         // 0..127
    const int kc = (idx & 7) * 8;   // 0..56
    union { u16 h[8]; uint4 v; } pk;
#pragma unroll
    for (int j = 0; j < 8; ++j) pk.h[j] = f2bf(t[kc + j][n]);
    *(uint4*)&Bt[(long)(n0 + n) * NN + k0 + kc] = pk.v;
  }
}

// ---------------------------------------------------------------------------
// Pass 2: R20 gemm (proven 39.2us) + FUSED SPLIT-K FIXUP: the reduce pass
// is folded into the gemm tail. Each chunk-writer of a multi-chunk tile:
// store (C or bf16 slab) -> __threadfence() (device-scope release, required
// across non-coherent XCD L2s) -> atomicAdd on the per-tile counter. The
// writer seeing count==nch-1 acquires and adds slabs into C -- same slab
// order as the old reduce kernel => identical values, deterministic.
// Fixup runs in the gemm's drain tail (idle CUs). Blocks >= nitems zero
// strictly-upper C tiles (nontemporal).
// ---------------------------------------------------------------------------
__global__ __launch_bounds__(512, 2) void gemm_tril(
    const u16* __restrict__ Ab, const u16* __restrict__ Bt,
    float* __restrict__ C, u16* __restrict__ P, int* __restrict__ cnt,
    int lg, int nitems) {
  extern __shared__ u16 lds[];  // [2][16384] A | [2][16384] B = 128 KB
  u16* AsB = lds;
  u16* BsB = lds + 32768;

  const int tid = threadIdx.x;

  if ((int)blockIdx.x >= nitems) {  // ---- zero a strictly-upper 256-tile ----
    int zi = blockIdx.x - nitems;   // 0..119
    int bi = 0;
    for (; bi < 15; ++bi) {
      const int u = 15 - bi;
      if (zi < u) break;
      zi -= u;
    }
    const int bj = bi + 1 + zi;
    const f32x4 z = {0.f, 0.f, 0.f, 0.f};
#pragma unroll
    for (int p = 0; p < 32; ++p) {
      const int idx = p * 512 + tid;
      const int row = idx >> 6;
      const int col = (idx & 63) * 4;
      __builtin_nontemporal_store(
          z, (f32x4*)&C[(long)(bi * 256 + row) * NN + bj * 256 + col]);
    }
    return;
  }

  const int lane = tid & 63;
  const int wid = tid >> 6;  // 0..7
  const int wm = wid >> 2;   // 0..1 (128-row half)
  const int wn = wid & 3;    // 0..3 (64-col block)
  const int sm = lane >> 3;
  const int sks = ((lane & 7) ^ sm) * 8;  // pre-swizzled source col (u16)
  const int rsel = lane & 7;

  // ---- decode blockIdx.x -> (bi, bj, chunk); 256-rows longest-K-first ----
  int rem = blockIdx.x, bi = 15, slabpre = 0, cntpre = 0;
  for (int s = 0; s < 16; ++s) {
    bi = 15 - s;
    const int fp = Fpre(bi + 1, lg);
    const int g = (bi + 1) + fp;
    if (rem < g) break;
    rem -= g;
    slabpre += fp;
    const int mc = bi + 1 - (1 << lg);
    cntpre += (mc > 0) ? mc : 0;
  }
  int bj = 0;
  for (;;) {
    const int c = ((bi - bj) >> lg) + 1;  // chunks of tile (bi,bj)
    if (rem < c) break;
    rem -= c;
    ++bj;
  }
  const int chunk = rem;
  const int nch = ((bi - bj) >> lg) + 1;
  const int L64 = 4 * (bi - bj + 1);
  const int H64 = 4 << lg;
  const int start = chunk * H64;
  const int nk = min(H64, L64 - start);
  const int rA = bi * 256;
  const int rB = bj * 256;
  const long kbase = (long)bj * 256 + (long)start * 64;

  f32x4 acc[8][4];
#pragma unroll
  for (int i = 0; i < 8; ++i)
#pragma unroll
    for (int j = 0; j < 4; ++j) acc[i][j] = (f32x4){0.f, 0.f, 0.f, 0.f};

  // stage part c (of 4) of K64-step kt into buffer b: 2 gload_lds16
#define STAGE_PART(kt, b, c)                                               \
  do {                                                                     \
    const long k0 = kbase + (long)(kt)*64;                                 \
    const int ch = wid * 4 + (c);                                          \
    gload_lds16(Ab + ((long)(rA + ch * 8 + sm) * NN + k0 + sks),           \
                AsB + (b)*16384 + ch * 512);                               \
    gload_lds16(Bt + ((long)(rB + ch * 8 + sm) * NN + k0 + sks),           \
                BsB + (b)*16384 + ch * 512);                               \
  } while (0)

#pragma unroll
  for (int c = 0; c < 4; ++c) STAGE_PART(0, 0, c);

  for (int kt = 0; kt < nk; ++kt) {
    const int cur = kt & 1;
    asm volatile("s_waitcnt vmcnt(0)" ::: "memory");  // own stage landed
    __builtin_amdgcn_s_barrier();                     // all waves' stage done
    __builtin_amdgcn_sched_barrier(0);                // no read hoists above

    const u16* As = AsB + cur * 16384;
    const u16* Bs = BsB + cur * 16384;
    const bool pf = (kt + 1 < nk);

    // B fragments (whole step) + A fragments for phase 0
    bf16x8 bb[4][2];
#pragma unroll
    for (int n4 = 0; n4 < 4; ++n4)
#pragma unroll
      for (int kk = 0; kk < 2; ++kk) {
        const int fr = wn * 64 + n4 * 16 + (lane & 15);
        const int slot = ((kk * 4 + (lane >> 4)) ^ rsel) * 8;
        bb[n4][kk] = *(const bf16x8*)&Bs[fr * 64 + slot];
      }
    bf16x8 aa[2][2][2];  // [phase&1][mm][kk]
#pragma unroll
    for (int mm = 0; mm < 2; ++mm)
#pragma unroll
      for (int kk = 0; kk < 2; ++kk) {
        const int fr = wm * 128 + mm * 16 + (lane & 15);
        const int slot = ((kk * 4 + (lane >> 4)) ^ rsel) * 8;
        aa[0][mm][kk] = *(const bf16x8*)&As[fr * 64 + slot];
      }

#pragma unroll
    for (int p = 0; p < 4; ++p) {
      if (pf && p < 2) {  // stage early (phases 0-1), 2 parts per phase
        STAGE_PART(kt + 1, cur ^ 1, 2 * p);
        STAGE_PART(kt + 1, cur ^ 1, 2 * p + 1);
      }
      if (p < 3) {  // prefetch next phase's A fragments
#pragma unroll
        for (int mm = 0; mm < 2; ++mm)
#pragma unroll
          for (int kk = 0; kk < 2; ++kk) {
            const int fr = wm * 128 + (2 * (p + 1) + mm) * 16 + (lane & 15);
            const int slot = ((kk * 4 + (lane >> 4)) ^ rsel) * 8;
            aa[(p + 1) & 1][mm][kk] = *(const bf16x8*)&As[fr * 64 + slot];
          }
        asm volatile("s_waitcnt lgkmcnt(4)" ::: "memory");  // cur frags done
      } else {
        asm volatile("s_waitcnt lgkmcnt(0)" ::: "memory");
      }
      __builtin_amdgcn_sched_barrier(0);  // rule #18: no MFMA hoist past wait
      __builtin_amdgcn_s_setprio(1);
#pragma unroll
      for (int kk = 0; kk < 2; ++kk)
#pragma unroll
        for (int mm = 0; mm < 2; ++mm)
#pragma unroll
          for (int n4 = 0; n4 < 4; ++n4)
            acc[2 * p + mm][n4] = __builtin_amdgcn_mfma_f32_16x16x32_bf16(
                aa[p & 1][mm][kk], bb[n4][kk], acc[2 * p + mm][n4], 0, 0, 0);
      __builtin_amdgcn_s_setprio(0);
    }
  }
#undef STAGE_PART

  // ---- epilogue: C/D layout col=lane&15, row=(lane>>4)*4+r ----
  const int lrow = wm * 128 + (lane >> 4) * 4;
  const int lcol = wn * 64 + (lane & 15);
  if (chunk == 0) {
    const bool diag = (bi == bj);
#pragma unroll
    for (int m4 = 0; m4 < 8; ++m4)
#pragma unroll
      for (int n4 = 0; n4 < 4; ++n4)
#pragma unroll
        for (int r = 0; r < 4; ++r) {
          const int gi = rA + lrow + m4 * 16 + r;
          const int gj = rB + lcol + n4 * 16;
          float v = acc[m4][n4][r];
          if (diag && gj > gi) v = 0.f;
          C[(long)gi * NN + gj] = v;
        }
  } else {
    const int slabidx =
        slabpre + (Fpre(bi + 1, lg) - Fpre(bi - bj + 1, lg)) + (chunk - 1);
    u16* slab = P + (long)slabidx * 65536;  // 256x256 bf16 = 128 KB
#pragma unroll
    for (int m4 = 0; m4 < 8; ++m4)
#pragma unroll
      for (int n4 = 0; n4 < 4; ++n4)
#pragma unroll
        for (int r = 0; r < 4; ++r)
          slab[(lrow + m4 * 16 + r) * 256 + lcol + n4 * 16] =
              f2bf(acc[m4][n4][r]);
  }

  // ---- fused split-K fixup (multi-chunk tiles only) ----
  if (nch >= 2) {
    const int tileCnt = cntpre + bj;  // multi-chunk tiles lead each row
    __threadfence();                  // release: stores visible device-wide
    __syncthreads();                  // whole block's stores fenced
    int* flag = (int*)lds;            // LDS long dead; reuse for broadcast
    if (tid == 0) *flag = atomicAdd(&cnt[tileCnt], 1);
    __syncthreads();
    if (*flag == nch - 1) {  // last writer: fold slabs into C
      __threadfence();       // acquire: see other writers' stores
      const int slabbase =
          slabpre + (Fpre(bi + 1, lg) - Fpre(bi - bj + 1, lg));
#pragma unroll
      for (int p = 0; p < 32; ++p) {
        const int idx = p * 512 + tid;  // 16384 float4 in 256x256 tile
        const int row = idx >> 6;
        const int col = (idx & 63) * 4;
        const long coff = (long)(rA + row) * NN + rB + col;
        float4 a4 = *(const float4*)&C[coff];
        for (int e = 0; e < nch - 1; ++e) {
          const ushort4 q = *(const ushort4*)&P[(long)(slabbase + e) * 65536 +
                                                row * 256 + col];
          a4.x += bf2f(q.x); a4.y += bf2f(q.y);
          a4.z += bf2f(q.z); a4.w += bf2f(q.w);
        }
        *(float4*)&C[coff] = a4;
      }
    }
  }
}

// ---------------------------------------------------------------------------
// Fallback (ws too small): naive fp32.
// ---------------------------------------------------------------------------
__global__ void naive_tril(const float* __restrict__ A,
                           const float* __restrict__ B, float* __restrict__ C) {
  const int j = blockIdx.x * 256 + threadIdx.x;
  const int i = blockIdx.y;
  float s = 0.f;
  for (int k = j; k <= i; ++k) s += A[(long)i * NN + k] * B[(long)k * NN + j];
  C[(long)i * NN + j] = s;
}

extern "C" void kernel_launch(void* const* d_in, const int* in_sizes, int n_in,
                              void* d_out, int out_size, void* d_ws,
                              size_t ws_size, hipStream_t stream) {
  const float* A = (const float*)d_in[0];
  const float* B = (const float*)d_in[1];
  float* C = (float*)d_out;

  const size_t opbytes = (size_t)2 * NN * NN * sizeof(u16);  // 64 MB operands
  const size_t slab = 131072;  // 256x256 bf16
  // tiers (+4 KB counters): lg=2 -> 124 slabs / 78 counters (proven best)
  const size_t need2 = opbytes + 124 * slab + 4096;
  const size_t need3 = opbytes + 36 * slab + 4096;

  if (ws_size < opbytes) {
    naive_tril<<<dim3(16, NN), 256, 0, stream>>>(A, B, C);
    return;
  }

  int lg, nitems, nslab;
  if (ws_size >= need2)      { lg = 2; nitems = 260; nslab = 124; }
  else if (ws_size >= need3) { lg = 3; nitems = 172; nslab = 36; }
  else                       { lg = 4; nitems = 136; nslab = 0; }

  u16* Ab = (u16*)d_ws;
  u16* Bt = Ab + (long)NN * NN;
  u16* P = (u16*)((char*)d_ws + opbytes);
  int* cnt = (int*)((char*)d_ws + opbytes + (size_t)nslab * slab);

  hipFuncSetAttribute((const void*)gemm_tril,
                      hipFuncAttributeMaxDynamicSharedMemorySize, 131072);

  if (nslab > 0)  // counters re-zeroed every replay (captured node)
    hipMemsetAsync(cnt, 0, 4096, stream);
  convert_fused<<<2144, 256, 0, stream>>>(A, B, Ab, Bt);
  gemm_tril<<<nitems + 120, 512, 131072, stream>>>(Ab, Bt, C, P, cnt, lg,
                                                   nitems);
}

// Round 22
// 78.190 us; speedup vs baseline: 2.4165x; 2.4165x over previous
//
#include <hip/hip_runtime.h>
#include <hip/hip_bf16.h>

#define NN 4096

typedef unsigned short u16;
typedef __attribute__((ext_vector_type(8))) short bf16x8;
typedef __attribute__((ext_vector_type(4))) float f32x4;

// fp32 -> bf16 round-to-nearest-even
static __device__ __forceinline__ u16 f2bf(float x) {
  unsigned u = __float_as_uint(x);
  u += 0x7fff + ((u >> 16) & 1);
  return (u16)(u >> 16);
}
static __device__ __forceinline__ float bf2f(u16 h) {
  return __uint_as_float((unsigned)h << 16);
}

// async global->LDS, 16B per lane; LDS dest = wave-uniform base + lane*16
static __device__ __forceinline__ void gload_lds16(const void* g, void* l) {
  __builtin_amdgcn_global_load_lds(
      (const __attribute__((address_space(1))) void*)g,
      (__attribute__((address_space(3))) void*)l, 16, 0, 0);
}

// F(M) = sum_{j=0}^{M-1} floor(j/2^lg)
static __device__ __forceinline__ int Fpre(int M, int lg) {
  if (M <= 0) return 0;
  const int q = (M - 1) >> lg, r = (M - 1) & ((1 << lg) - 1);
  return ((q * (q - 1)) << (lg - 1)) + q * (r + 1);
}

// ---------------------------------------------------------------------------
// Pass 1 (fused, grid 2144): A-path 16B stores / 16 loads in flight;
// B-path 64k x 128n transpose tiles, 8 loads in flight.
// ---------------------------------------------------------------------------
__global__ __launch_bounds__(256) void convert_fused(
    const float* __restrict__ A, const float* __restrict__ B,
    u16* __restrict__ Ab, u16* __restrict__ Bt) {
  __shared__ float t[64][129];  // 33 KB
  const int blk = blockIdx.x;
  const int tid = threadIdx.x;

  if (blk < 1024) {  // ---- A path: 128x128 block (bi,kb) ----
    const int kb = blk & 31, bi = blk >> 5;
    if (kb > bi) {
      if (kb == bi + 1 && !(bi & 1)) {  // super-diagonal Ab: real zeros
        const uint4 zz = {0u, 0u, 0u, 0u};
        const int r0 = tid >> 4;
        const int cq = (tid & 15) * 8;
#pragma unroll
        for (int h = 0; h < 8; ++h)
          *(uint4*)&Ab[(long)(bi * 128 + h * 16 + r0) * NN + kb * 128 + cq] =
              zz;
      }
      return;
    }
    const int r0 = tid >> 4;        // 0..15
    const int cq = (tid & 15) * 8;  // 8 cols per thread
    const bool diag = (kb == bi);
    float4 v0[8], v1[8];
#pragma unroll
    for (int h = 0; h < 8; ++h) {  // 16 loads in flight
      const float* src =
          &A[(long)(bi * 128 + h * 16 + r0) * NN + kb * 128 + cq];
      v0[h] = *(const float4*)src;
      v1[h] = *(const float4*)(src + 4);
    }
#pragma unroll
    for (int h = 0; h < 8; ++h) {
      const int row = h * 16 + r0;
      union { u16 e[8]; uint4 v; } o;
      o.e[0] = f2bf(v0[h].x); o.e[1] = f2bf(v0[h].y);
      o.e[2] = f2bf(v0[h].z); o.e[3] = f2bf(v0[h].w);
      o.e[4] = f2bf(v1[h].x); o.e[5] = f2bf(v1[h].y);
      o.e[6] = f2bf(v1[h].z); o.e[7] = f2bf(v1[h].w);
      if (diag) {
        const int i = bi * 128 + row, k = kb * 128 + cq;
#pragma unroll
        for (int e = 0; e < 8; ++e)
          if (k + e > i) o.e[e] = 0;
      }
      *(uint4*)&Ab[(long)(bi * 128 + row) * NN + kb * 128 + cq] = o.v;
    }
    return;
  }

  if (blk >= 2080) {  // ---- sub-diagonal Bt zero blocks ----
    const int idx = blk - 2080;  // 0..63
    const int q = idx >> 2;
    const int n0 = (2 * (2 * q + 1) + (idx & 1)) * 64;
    const int k0 = (2 * (2 * q) + ((idx >> 1) & 1)) * 64;
    const int n = tid >> 3;
    const int kc = (tid & 7) * 8;
    const uint4 z = {0u, 0u, 0u, 0u};
#pragma unroll
    for (int p = 0; p < 2; ++p)
      *(uint4*)&Bt[(long)(n0 + n + p * 32) * NN + k0 + kc] = z;
    return;
  }

  // ---- B path: 64k x 128n transpose tile over needed (N<=K) 128-pairs ----
  const int t2 = blk - 1024;  // 0..1055
  int prem = t2 >> 1, N = 0;  // pair index 0..527
  while (prem >= 32 - N) { prem -= 32 - N; ++N; }
  const int K = N + prem;     // N <= K
  const int n0 = N * 128;
  const int k0 = K * 128 + (t2 & 1) * 64;

  float4 w[8];
#pragma unroll
  for (int p = 0; p < 8; ++p) {  // 8 loads in flight (ILP)
    const int idx = p * 256 + tid;
    const int r = idx >> 5;          // 0..63 (k row)
    const int c4 = (idx & 31) * 4;   // 0..124 (n col quad)
    w[p] = *(const float4*)&B[(long)(k0 + r) * NN + n0 + c4];
  }
#pragma unroll
  for (int p = 0; p < 8; ++p) {
    const int idx = p * 256 + tid;
    const int r = idx >> 5;
    const int c4 = (idx & 31) * 4;
    const int kg = k0 + r;
    t[r][c4 + 0] = (n0 + c4 + 0 <= kg) ? w[p].x : 0.f;
    t[r][c4 + 1] = (n0 + c4 + 1 <= kg) ? w[p].y : 0.f;
    t[r][c4 + 2] = (n0 + c4 + 2 <= kg) ? w[p].z : 0.f;
    t[r][c4 + 3] = (n0 + c4 + 3 <= kg) ? w[p].w : 0.f;
  }
  __syncthreads();

#pragma unroll
  for (int q = 0; q < 4; ++q) {
    const int idx = q * 256 + tid;
    const int n = idx >> 3;         // 0..127
    const int kc = (idx & 7) * 8;   // 0..56
    union { u16 h[8]; uint4 v; } pk;
#pragma unroll
    for (int j = 0; j < 8; ++j) pk.h[j] = f2bf(t[kc + j][n]);
    *(uint4*)&Bt[(long)(n0 + n) * NN + k0 + kc] = pk.v;
  }
}

// ---------------------------------------------------------------------------
// Pass 2: lean 1-barrier step, lgkmcnt(4) phase pipeline, stage at phases
// 0-1, T2 swizzle, bf16 slabs, nontemporal zero tail tiles. (R20 proven;
// R21's fused fixup fence caused an L2 writeback storm -- reverted. The
// kernel-launch boundary is the cheapest device-wide fence.)
// ---------------------------------------------------------------------------
__global__ __launch_bounds__(512, 2) void gemm_tril(
    const u16* __restrict__ Ab, const u16* __restrict__ Bt,
    float* __restrict__ C, u16* __restrict__ P, int lg, int nitems) {
  extern __shared__ u16 lds[];  // [2][16384] A | [2][16384] B = 128 KB
  u16* AsB = lds;
  u16* BsB = lds + 32768;

  const int tid = threadIdx.x;

  if ((int)blockIdx.x >= nitems) {  // ---- zero a strictly-upper 256-tile ----
    int zi = blockIdx.x - nitems;   // 0..119
    int bi = 0;
    for (; bi < 15; ++bi) {
      const int u = 15 - bi;
      if (zi < u) break;
      zi -= u;
    }
    const int bj = bi + 1 + zi;
    const f32x4 z = {0.f, 0.f, 0.f, 0.f};
#pragma unroll
    for (int p = 0; p < 32; ++p) {
      const int idx = p * 512 + tid;
      const int row = idx >> 6;
      const int col = (idx & 63) * 4;
      __builtin_nontemporal_store(
          z, (f32x4*)&C[(long)(bi * 256 + row) * NN + bj * 256 + col]);
    }
    return;
  }

  const int lane = tid & 63;
  const int wid = tid >> 6;  // 0..7
  const int wm = wid >> 2;   // 0..1 (128-row half)
  const int wn = wid & 3;    // 0..3 (64-col block)
  const int sm = lane >> 3;
  const int sks = ((lane & 7) ^ sm) * 8;  // pre-swizzled source col (u16)
  const int rsel = lane & 7;

  // ---- decode blockIdx.x -> (bi, bj, chunk); 256-rows longest-K-first ----
  int rem = blockIdx.x, bi = 15, slabpre = 0;
  for (int s = 0; s < 16; ++s) {
    bi = 15 - s;
    const int fp = Fpre(bi + 1, lg);
    const int g = (bi + 1) + fp;
    if (rem < g) break;
    rem -= g;
    slabpre += fp;
  }
  int bj = 0;
  for (;;) {
    const int c = ((bi - bj) >> lg) + 1;  // chunks of tile (bi,bj)
    if (rem < c) break;
    rem -= c;
    ++bj;
  }
  const int chunk = rem;
  const int L64 = 4 * (bi - bj + 1);
  const int H64 = 4 << lg;
  const int start = chunk * H64;
  const int nk = min(H64, L64 - start);
  const int rA = bi * 256;
  const int rB = bj * 256;
  const long kbase = (long)bj * 256 + (long)start * 64;

  f32x4 acc[8][4];
#pragma unroll
  for (int i = 0; i < 8; ++i)
#pragma unroll
    for (int j = 0; j < 4; ++j) acc[i][j] = (f32x4){0.f, 0.f, 0.f, 0.f};

  // stage part c (of 4) of K64-step kt into buffer b: 2 gload_lds16
#define STAGE_PART(kt, b, c)                                               \
  do {                                                                     \
    const long k0 = kbase + (long)(kt)*64;                                 \
    const int ch = wid * 4 + (c);                                          \
    gload_lds16(Ab + ((long)(rA + ch * 8 + sm) * NN + k0 + sks),           \
                AsB + (b)*16384 + ch * 512);                               \
    gload_lds16(Bt + ((long)(rB + ch * 8 + sm) * NN + k0 + sks),           \
                BsB + (b)*16384 + ch * 512);                               \
  } while (0)

#pragma unroll
  for (int c = 0; c < 4; ++c) STAGE_PART(0, 0, c);

  for (int kt = 0; kt < nk; ++kt) {
    const int cur = kt & 1;
    asm volatile("s_waitcnt vmcnt(0)" ::: "memory");  // own stage landed
    __builtin_amdgcn_s_barrier();                     // all waves' stage done
    __builtin_amdgcn_sched_barrier(0);                // no read hoists above

    const u16* As = AsB + cur * 16384;
    const u16* Bs = BsB + cur * 16384;
    const bool pf = (kt + 1 < nk);

    // B fragments (whole step) + A fragments for phase 0
    bf16x8 bb[4][2];
#pragma unroll
    for (int n4 = 0; n4 < 4; ++n4)
#pragma unroll
      for (int kk = 0; kk < 2; ++kk) {
        const int fr = wn * 64 + n4 * 16 + (lane & 15);
        const int slot = ((kk * 4 + (lane >> 4)) ^ rsel) * 8;
        bb[n4][kk] = *(const bf16x8*)&Bs[fr * 64 + slot];
      }
    bf16x8 aa[2][2][2];  // [phase&1][mm][kk]
#pragma unroll
    for (int mm = 0; mm < 2; ++mm)
#pragma unroll
      for (int kk = 0; kk < 2; ++kk) {
        const int fr = wm * 128 + mm * 16 + (lane & 15);
        const int slot = ((kk * 4 + (lane >> 4)) ^ rsel) * 8;
        aa[0][mm][kk] = *(const bf16x8*)&As[fr * 64 + slot];
      }

#pragma unroll
    for (int p = 0; p < 4; ++p) {
      if (pf && p < 2) {  // stage early (phases 0-1), 2 parts per phase
        STAGE_PART(kt + 1, cur ^ 1, 2 * p);
        STAGE_PART(kt + 1, cur ^ 1, 2 * p + 1);
      }
      if (p < 3) {  // prefetch next phase's A fragments
#pragma unroll
        for (int mm = 0; mm < 2; ++mm)
#pragma unroll
          for (int kk = 0; kk < 2; ++kk) {
            const int fr = wm * 128 + (2 * (p + 1) + mm) * 16 + (lane & 15);
            const int slot = ((kk * 4 + (lane >> 4)) ^ rsel) * 8;
            aa[(p + 1) & 1][mm][kk] = *(const bf16x8*)&As[fr * 64 + slot];
          }
        asm volatile("s_waitcnt lgkmcnt(4)" ::: "memory");  // cur frags done
      } else {
        asm volatile("s_waitcnt lgkmcnt(0)" ::: "memory");
      }
      __builtin_amdgcn_sched_barrier(0);  // rule #18: no MFMA hoist past wait
      __builtin_amdgcn_s_setprio(1);
#pragma unroll
      for (int kk = 0; kk < 2; ++kk)
#pragma unroll
        for (int mm = 0; mm < 2; ++mm)
#pragma unroll
          for (int n4 = 0; n4 < 4; ++n4)
            acc[2 * p + mm][n4] = __builtin_amdgcn_mfma_f32_16x16x32_bf16(
                aa[p & 1][mm][kk], bb[n4][kk], acc[2 * p + mm][n4], 0, 0, 0);
      __builtin_amdgcn_s_setprio(0);
    }
  }
#undef STAGE_PART

  // ---- epilogue: C/D layout col=lane&15, row=(lane>>4)*4+r ----
  const int lrow = wm * 128 + (lane >> 4) * 4;
  const int lcol = wn * 64 + (lane & 15);
  if (chunk == 0) {
    const bool diag = (bi == bj);
#pragma unroll
    for (int m4 = 0; m4 < 8; ++m4)
#pragma unroll
      for (int n4 = 0; n4 < 4; ++n4)
#pragma unroll
        for (int r = 0; r < 4; ++r) {
          const int gi = rA + lrow + m4 * 16 + r;
          const int gj = rB + lcol + n4 * 16;
          float v = acc[m4][n4][r];
          if (diag && gj > gi) v = 0.f;
          C[(long)gi * NN + gj] = v;
        }
  } else {
    const int slabidx =
        slabpre + (Fpre(bi + 1, lg) - Fpre(bi - bj + 1, lg)) + (chunk - 1);
    u16* slab = P + (long)slabidx * 65536;  // 256x256 bf16 = 128 KB
#pragma unroll
    for (int m4 = 0; m4 < 8; ++m4)
#pragma unroll
      for (int n4 = 0; n4 < 4; ++n4)
#pragma unroll
        for (int r = 0; r < 4; ++r)
          slab[(lrow + m4 * 16 + r) * 256 + lcol + n4 * 16] =
              f2bf(acc[m4][n4][r]);
  }
}

// ---------------------------------------------------------------------------
// Pass 3: add bf16 partial slabs into C. Multi-chunk tiles only
// (bi-bj >= 2^lg), 4 row-stripes per tile.
// ---------------------------------------------------------------------------
__global__ __launch_bounds__(256) void reduce_partials(
    float* __restrict__ C, const u16* __restrict__ P, int lg) {
  const int G = 1 << lg;
  const int tb = blockIdx.x >> 2;
  const int stripe = blockIdx.x & 3;
  int rem = tb, bi = 15, slabpre = 0;
  for (int s = 0; s < 16; ++s) {
    bi = 15 - s;
    const int g = (bi + 1 - G > 0) ? bi + 1 - G : 0;
    if (rem < g) break;
    rem -= g;
    slabpre += Fpre(bi + 1, lg);
  }
  const int bj = rem;  // bj <= bi-G -> nch >= 2
  const int nch = ((bi - bj) >> lg) + 1;
  const int slaboff = slabpre + (Fpre(bi + 1, lg) - Fpre(bi - bj + 1, lg));

  const int tid = threadIdx.x;
#pragma unroll
  for (int p = 0; p < 16; ++p) {
    const int idx = p * 256 + tid;  // 4096 float4 per 64-row stripe
    const int row = stripe * 64 + (idx >> 6);
    const int col = (idx & 63) * 4;
    const long coff = (long)(bi * 256 + row) * NN + bj * 256 + col;
    float4 acc = *(const float4*)&C[coff];
    for (int e = 0; e < nch - 1; ++e) {
      const ushort4 q =
          *(const ushort4*)&P[(long)(slaboff + e) * 65536 + row * 256 + col];
      acc.x += bf2f(q.x); acc.y += bf2f(q.y);
      acc.z += bf2f(q.z); acc.w += bf2f(q.w);
    }
    *(float4*)&C[coff] = acc;
  }
}

// ---------------------------------------------------------------------------
// Fallback (ws too small): naive fp32.
// ---------------------------------------------------------------------------
__global__ void naive_tril(const float* __restrict__ A,
                           const float* __restrict__ B, float* __restrict__ C) {
  const int j = blockIdx.x * 256 + threadIdx.x;
  const int i = blockIdx.y;
  float s = 0.f;
  for (int k = j; k <= i; ++k) s += A[(long)i * NN + k] * B[(long)k * NN + j];
  C[(long)i * NN + j] = s;
}

extern "C" void kernel_launch(void* const* d_in, const int* in_sizes, int n_in,
                              void* d_out, int out_size, void* d_ws,
                              size_t ws_size, hipStream_t stream) {
  const float* A = (const float*)d_in[0];
  const float* B = (const float*)d_in[1];
  float* C = (float*)d_out;

  const size_t opbytes = (size_t)2 * NN * NN * sizeof(u16);  // 64 MB operands
  const size_t slab = 131072;  // 256x256 bf16
  const size_t need2 = opbytes + 124 * slab;  // 79.5 MB (lg=2, proven best)
  const size_t need3 = opbytes + 36 * slab;

  if (ws_size < opbytes) {
    naive_tril<<<dim3(16, NN), 256, 0, stream>>>(A, B, C);
    return;
  }

  int lg, nitems, nred;
  if (ws_size >= need2)      { lg = 2; nitems = 260; nred = 78; }
  else if (ws_size >= need3) { lg = 3; nitems = 172; nred = 36; }
  else                       { lg = 4; nitems = 136; nred = 0; }

  u16* Ab = (u16*)d_ws;
  u16* Bt = Ab + (long)NN * NN;
  u16* P = (u16*)((char*)d_ws + opbytes);

  hipFuncSetAttribute((const void*)gemm_tril,
                      hipFuncAttributeMaxDynamicSharedMemorySize, 131072);

  convert_fused<<<2144, 256, 0, stream>>>(A, B, Ab, Bt);
  gemm_tril<<<nitems + 120, 512, 131072, stream>>>(Ab, Bt, C, P, lg, nitems);
  if (nred > 0) reduce_partials<<<nred * 4, 256, 0, stream>>>(C, P, lg);
}